// Round 1
// baseline (43.918 us; speedup 1.0000x reference)
//
#include <hip/hip_runtime.h>
#include <hip/hip_bf16.h>
#include <math.h>

#define IMG 224
#define NLIB 1000
#define ZD 512
#define MAXK 8

// ---------------- ws layout (floats) ----------------
// [0, 1000)                    dists
// [1024, 1024+16)              selected indices (int view)
// [1040, +8*3136)              s0k  (per-k channel-L2 sums, scale 0, 56x56)
// next 8*784                   s1k  (28x28)
// next 8*196                   s2k  (14x14)
// next 50176                   pre-blur 224x224
// next 50176                   mid-blur 224x224
// total ~134k floats (~537 KB)

__device__ __forceinline__ int clampk(int k) {
    if (k < 1) k = 1;
    if (k > MAXK) k = MAXK;
    return k;
}

// ---- 1. dists[e] = || z_lib[e] - z ||  (one wave per entry) ----
__global__ void k_dist(const float* __restrict__ z, const float* __restrict__ zlib,
                       float* __restrict__ dists) {
    int e = blockIdx.x;
    int lane = threadIdx.x;           // 64 lanes
    const float* row = zlib + (size_t)e * ZD;
    float acc = 0.f;
#pragma unroll
    for (int j = 0; j < ZD / 64; ++j) {
        float d = row[j * 64 + lane] - z[j * 64 + lane];
        acc += d * d;
    }
#pragma unroll
    for (int off = 32; off > 0; off >>= 1) acc += __shfl_xor(acc, off, 64);
    if (lane == 0) dists[e] = sqrtf(acc);
}

// ---- 2. top-k smallest + z_score (single block) ----
__global__ void k_topk(const float* __restrict__ dists, const int* __restrict__ kp,
                       int* __restrict__ idx_out, float* __restrict__ zscore_out) {
    __shared__ float sv[1024];
    __shared__ int   si[1024];
    int tid = threadIdx.x;
    int k = clampk(*kp);
    float v = (tid < NLIB) ? dists[tid] : 3.4e38f;
    float ssum = 0.f;
    for (int it = 0; it < k; ++it) {
        sv[tid] = v; si[tid] = tid;
        __syncthreads();
        for (int s = 512; s > 0; s >>= 1) {
            if (tid < s) {
                if (sv[tid + s] < sv[tid]) { sv[tid] = sv[tid + s]; si[tid] = si[tid + s]; }
            }
            __syncthreads();
        }
        float selv = sv[0];
        int   seli = si[0];
        __syncthreads();                 // everyone read sv[0]/si[0] before reuse
        if (tid == seli) v = 3.4e38f;
        if (tid == 0) { idx_out[it] = seli; ssum += selv; }
    }
    if (tid == 0) *zscore_out = ssum / (float)k;
}

// ---- 3. per-(pixel, kk) channel-L2 sums for all 3 scales ----
__global__ void k_score(const float* __restrict__ f0, const float* __restrict__ f1,
                        const float* __restrict__ f2,
                        const float* __restrict__ l0, const float* __restrict__ l1,
                        const float* __restrict__ l2,
                        const int* __restrict__ idx, const int* __restrict__ kp,
                        float* __restrict__ s0, float* __restrict__ s1,
                        float* __restrict__ s2) {
    int g = blockIdx.x * blockDim.x + threadIdx.x;
    int k = clampk(*kp);

    const float* fm; const float* lib; float* out; int C, HW, q;
    const int S0 = MAXK * 3136, S1 = MAXK * 784, S2 = MAXK * 196;
    if (g < S0)            { q = g;            C = 64;  HW = 3136; fm = f0; lib = l0; out = s0; }
    else if (g < S0 + S1)  { q = g - S0;       C = 128; HW = 784;  fm = f1; lib = l1; out = s1; }
    else if (g < S0 + S1 + S2) { q = g - S0 - S1; C = 256; HW = 196; fm = f2; lib = l2; out = s2; }
    else return;

    int kk = q / HW;
    int p  = q % HW;
    if (kk >= k) return;

    const float* le = lib + (size_t)idx[kk] * (size_t)C * HW + p;
    const float* fe = fm + p;
    float acc = 0.f;
#pragma unroll 8
    for (int c = 0; c < C; ++c) {
        float d = le[(size_t)c * HW] - fe[(size_t)c * HW];
        acc += d * d;
    }
    out[kk * HW + p] = acc;   // sum of squares; sqrt+min later
}

// ---- 4. min-over-k + sqrt + bilinear upsample + sum over scales ----
__device__ __forceinline__ float scale_sample(const float* __restrict__ sk, int Win,
                                              float scl, int k, int x, int y) {
    int HW = Win * Win;
    float sxf = ((float)x + 0.5f) * scl - 0.5f;
    float syf = ((float)y + 0.5f) * scl - 0.5f;
    float fx = floorf(sxf), fy = floorf(syf);
    float wx = sxf - fx,    wy = syf - fy;
    int x0 = (int)fx, y0 = (int)fy;
    int x0c = min(max(x0, 0), Win - 1), x1c = min(max(x0 + 1, 0), Win - 1);
    int y0c = min(max(y0, 0), Win - 1), y1c = min(max(y0 + 1, 0), Win - 1);

    float v[4];
    int cx[4] = {x0c, x1c, x0c, x1c};
    int cy[4] = {y0c, y0c, y1c, y1c};
#pragma unroll
    for (int c = 0; c < 4; ++c) {
        int o = cy[c] * Win + cx[c];
        float mn = sk[o];
        for (int kk = 1; kk < k; ++kk) mn = fminf(mn, sk[kk * HW + o]);
        v[c] = sqrtf(mn);
    }
    return (1.f - wy) * ((1.f - wx) * v[0] + wx * v[1]) +
           wy * ((1.f - wx) * v[2] + wx * v[3]);
}

__global__ void k_upsample(const float* __restrict__ s0, const float* __restrict__ s1,
                           const float* __restrict__ s2, const int* __restrict__ kp,
                           float* __restrict__ pre) {
    int g = blockIdx.x * blockDim.x + threadIdx.x;
    if (g >= IMG * IMG) return;
    int k = clampk(*kp);
    int y = g / IMG, x = g % IMG;
    float v = scale_sample(s0, 56, 0.25f,   k, x, y)
            + scale_sample(s1, 28, 0.125f,  k, x, y)
            + scale_sample(s2, 14, 0.0625f, k, x, y);
    pre[g] = v;
}

// ---- 5/6. separable gaussian blur, zero-padded SAME ----
__global__ void k_blurh(const float* __restrict__ in, float* __restrict__ out) {
    int g = blockIdx.x * blockDim.x + threadIdx.x;
    if (g >= IMG * IMG) return;
    int y = g / IMG, x = g % IMG;
    float acc = 0.f, wsum = 0.f;
#pragma unroll
    for (int t = -8; t <= 8; ++t) {
        float r = (float)t * 0.25f;           // t / sigma, sigma=4
        float w = expf(-0.5f * r * r);
        wsum += w;
        int xx = x + t;
        if ((unsigned)xx < (unsigned)IMG) acc += w * in[y * IMG + xx];
    }
    out[g] = acc / wsum;
}

__global__ void k_blurv(const float* __restrict__ in, float* __restrict__ out) {
    int g = blockIdx.x * blockDim.x + threadIdx.x;
    if (g >= IMG * IMG) return;
    int y = g / IMG, x = g % IMG;
    float acc = 0.f, wsum = 0.f;
#pragma unroll
    for (int t = -8; t <= 8; ++t) {
        float r = (float)t * 0.25f;
        float w = expf(-0.5f * r * r);
        wsum += w;
        int yy = y + t;
        if ((unsigned)yy < (unsigned)IMG) acc += w * in[yy * IMG + x];
    }
    out[g] = acc / wsum;
}

extern "C" void kernel_launch(void* const* d_in, const int* in_sizes, int n_in,
                              void* d_out, int out_size, void* d_ws, size_t ws_size,
                              hipStream_t stream) {
    const float* z    = (const float*)d_in[0];
    const float* f0   = (const float*)d_in[1];
    const float* f1   = (const float*)d_in[2];
    const float* f2   = (const float*)d_in[3];
    const float* zlib = (const float*)d_in[4];
    const float* l0   = (const float*)d_in[5];
    const float* l1   = (const float*)d_in[6];
    const float* l2   = (const float*)d_in[7];
    const int*   kp   = (const int*)d_in[8];
    float* out = (float*)d_out;

    float* ws    = (float*)d_ws;
    float* dists = ws;                      // 1000
    int*   idx   = (int*)(ws + 1024);       // 16
    float* s0    = ws + 1040;               // 8*3136
    float* s1    = s0 + MAXK * 3136;        // 8*784
    float* s2    = s1 + MAXK * 784;         // 8*196
    float* pre   = s2 + MAXK * 196;         // 50176
    float* mid   = pre + IMG * IMG;         // 50176

    k_dist<<<NLIB, 64, 0, stream>>>(z, zlib, dists);
    k_topk<<<1, 1024, 0, stream>>>(dists, kp, idx, out);   // writes d_out[0]

    int total = MAXK * (3136 + 784 + 196);                 // 32928
    k_score<<<(total + 255) / 256, 256, 0, stream>>>(f0, f1, f2, l0, l1, l2,
                                                     idx, kp, s0, s1, s2);
    k_upsample<<<(IMG * IMG + 255) / 256, 256, 0, stream>>>(s0, s1, s2, kp, pre);
    k_blurh<<<(IMG * IMG + 255) / 256, 256, 0, stream>>>(pre, mid);
    k_blurv<<<(IMG * IMG + 255) / 256, 256, 0, stream>>>(mid, out + 1);
}